// Round 2
// baseline (438.014 us; speedup 1.0000x reference)
//
#include <hip/hip_runtime.h>
#include <hip/hip_fp16.h>

#define CCH 64
#define NBLK 128        // phase-A partition blocks
#define BKT  256        // nodes per bucket
#define PB   64         // perm-scatter blocks

// ---------------- Phase A: partitioned counting sort of edges by dst ----------------

__global__ void countA(const int* __restrict__ dst, int* __restrict__ cntmat,
                       int* __restrict__ ghist, int E, int chunk, int B) {
    __shared__ int h[512];
    int t = threadIdx.x, blk = blockIdx.x;
    if (blk == 0) ghist[t] = 0;          // re-zero degree histogram every launch
    for (int i = t; i < B; i += 256) h[i] = 0;
    __syncthreads();
    int e0 = blk * chunk, e1 = min(e0 + chunk, E);
    for (int e = e0 + t; e < e1; e += 256) atomicAdd(&h[dst[e] >> 8], 1);
    __syncthreads();
    for (int i = t; i < B; i += 256) cntmat[i * NBLK + blk] = h[i];
}

// Two-level exclusive scan (1024 elems / block)
__global__ void scan1(const int* __restrict__ cnt, int* __restrict__ part,
                      int* __restrict__ bsum, int N) {
    __shared__ int s[256];
    int t = threadIdx.x;
    int base = blockIdx.x * 1024 + t * 4;
    int v0 = (base + 0 < N) ? cnt[base + 0] : 0;
    int v1 = (base + 1 < N) ? cnt[base + 1] : 0;
    int v2 = (base + 2 < N) ? cnt[base + 2] : 0;
    int v3 = (base + 3 < N) ? cnt[base + 3] : 0;
    s[t] = v0 + v1 + v2 + v3;
    __syncthreads();
    for (int off = 1; off < 256; off <<= 1) {
        int xx = (t >= off) ? s[t - off] : 0;
        __syncthreads();
        s[t] += xx;
        __syncthreads();
    }
    int excl = (t == 0) ? 0 : s[t - 1];
    if (t == 255) bsum[blockIdx.x] = s[255];
    if (base + 0 < N) part[base + 0] = excl;
    if (base + 1 < N) part[base + 1] = excl + v0;
    if (base + 2 < N) part[base + 2] = excl + v0 + v1;
    if (base + 3 < N) part[base + 3] = excl + v0 + v1 + v2;
}

__global__ void scan2(int* __restrict__ bsum, int NB) {
    __shared__ int s[256];
    int t = threadIdx.x;
    int base = t * 4;
    int v0 = (base + 0 < NB) ? bsum[base + 0] : 0;
    int v1 = (base + 1 < NB) ? bsum[base + 1] : 0;
    int v2 = (base + 2 < NB) ? bsum[base + 2] : 0;
    int v3 = (base + 3 < NB) ? bsum[base + 3] : 0;
    s[t] = v0 + v1 + v2 + v3;
    __syncthreads();
    for (int off = 1; off < 256; off <<= 1) {
        int xx = (t >= off) ? s[t - off] : 0;
        __syncthreads();
        s[t] += xx;
        __syncthreads();
    }
    int excl = (t == 0) ? 0 : s[t - 1];
    if (base + 0 < NB) bsum[base + 0] = excl;
    if (base + 1 < NB) bsum[base + 1] = excl + v0;
    if (base + 2 < NB) bsum[base + 2] = excl + v0 + v1;
    if (base + 3 < NB) bsum[base + 3] = excl + v0 + v1 + v2;
}

// partition: write (src<<8 | dst&255) into per-(block,bucket) exclusive ranges.
__global__ void partA(const int* __restrict__ src, const int* __restrict__ dst,
                      const int* __restrict__ part, const int* __restrict__ bsum,
                      unsigned* __restrict__ brec, int E, int chunk, int B) {
    __shared__ int cur[512];
    int t = threadIdx.x, blk = blockIdx.x;
    for (int i = t; i < B; i += 256) {
        int idx = i * NBLK + blk;
        cur[i] = part[idx] + bsum[idx >> 10];
    }
    __syncthreads();
    int e0 = blk * chunk, e1 = min(e0 + chunk, E);
    for (int e = e0 + t; e < e1; e += 256) {
        int s = src[e], d = dst[e];
        int pos = atomicAdd(&cur[d >> 8], 1);
        brec[pos] = ((unsigned)s << 8) | (unsigned)(d & 255);
    }
}

// ---------------- Phase B: per-bucket CSR finalize + u0 = fp16(dinv*x) ----------------
// Also pre-aggregates the per-degree node histogram (for the degree-sorted
// node permutation) into ghist via one LDS histogram + <=32 global atomics.
__global__ void buildB(const unsigned* __restrict__ brec, const int* __restrict__ part,
                       const int* __restrict__ bsum, int* __restrict__ row_ptr,
                       int* __restrict__ adj, float* __restrict__ dinv,
                       float* __restrict__ dinv2, const float* __restrict__ x,
                       __half* __restrict__ xh, int* __restrict__ ghist,
                       int N, int B, int E) {
    __shared__ int hist[256];
    __shared__ int scanbuf[256];
    __shared__ int cursor[256];
    __shared__ int dh[256];
    __shared__ float sdinv[256];
    int t = threadIdx.x, k = blockIdx.x;
    int i0 = k * NBLK;
    int base = part[i0] + bsum[i0 >> 10];
    int nextb;
    if (k + 1 < B) {
        int i1 = (k + 1) * NBLK;
        nextb = part[i1] + bsum[i1 >> 10];
    } else {
        nextb = E;
    }
    hist[t] = 0;
    dh[t] = 0;
    __syncthreads();
    for (int i = base + t; i < nextb; i += 256) atomicAdd(&hist[brec[i] & 255u], 1);
    __syncthreads();
    int v = hist[t];
    scanbuf[t] = v;
    __syncthreads();
    for (int o = 1; o < 256; o <<= 1) {
        int xx = (t >= o) ? scanbuf[t - o] : 0;
        __syncthreads();
        scanbuf[t] += xx;
        __syncthreads();
    }
    int excl = scanbuf[t] - v;
    int node = k * 256 + t;
    float di = 0.f;
    if (node < N) {
        int p = base + excl;
        row_ptr[node] = p;
        cursor[t] = p;
        float dp1 = (float)v + 1.0f;          // degree incl. self-loop
        di = rsqrtf(dp1);
        dinv[node]  = di;
        dinv2[node] = 1.0f / dp1;
        atomicAdd(&dh[v < 255 ? v : 255], 1); // degree histogram (LDS)
    }
    sdinv[t] = di;
    if (k == 0 && t == 0) row_ptr[N] = E;
    __syncthreads();
    if (dh[t]) atomicAdd(&ghist[t], dh[t]);
    for (int i = base + t; i < nextb; i += 256) {
        unsigned r = brec[i];
        int pos = atomicAdd(&cursor[r & 255u], 1);
        adj[pos] = (int)(r >> 8);
    }
    // fused tohalf for this bucket (coalesced; overlaps scatter latency)
    int nodeBase = k * 256;
    for (int i = t; i < 2048; i += 256) {
        int nl = i >> 3;
        int node2 = nodeBase + nl;
        if (node2 < N) {
            float d = sdinv[nl];
            size_t baseE = (size_t)node2 * 64 + (size_t)(i & 7) * 8;
            float4 a = *(const float4*)&x[baseE];
            float4 c = *(const float4*)&x[baseE + 4];
            float4 o;
            __half2* op = (__half2*)&o;
            op[0] = __float22half2_rn(make_float2(d * a.x, d * a.y));
            op[1] = __float22half2_rn(make_float2(d * a.z, d * a.w));
            op[2] = __float22half2_rn(make_float2(d * c.x, d * c.y));
            op[3] = __float22half2_rn(make_float2(d * c.z, d * c.w));
            *(float4*)&xh[baseE] = o;
        }
    }
}

// ---------------- degree-sorted node permutation ----------------
// permScan: exclusive scan of the 256-bin degree histogram (in place).
__global__ void permScan(int* __restrict__ h) {
    __shared__ int s[256];
    int t = threadIdx.x;
    int v = h[t];
    s[t] = v;
    __syncthreads();
    for (int o = 1; o < 256; o <<= 1) {
        int xx = (t >= o) ? s[t - o] : 0;
        __syncthreads();
        s[t] += xx;
        __syncthreads();
    }
    h[t] = s[t] - v;
}

// permScatter: rank nodes by degree. Per-block LDS histogram, reserve global
// ranges per bin (one atomic per nonzero bin), then scatter via LDS cursors.
__global__ void permScatter(const int* __restrict__ row_ptr, int* __restrict__ goff,
                            int* __restrict__ perm, int N, int chunk) {
    __shared__ int h[256];
    __shared__ int cur[256];
    int t = threadIdx.x, blk = blockIdx.x;
    h[t] = 0;
    __syncthreads();
    int n0 = blk * chunk, n1 = min(n0 + chunk, N);
    for (int n = n0 + t; n < n1; n += 256) {
        int d = row_ptr[n + 1] - row_ptr[n];
        atomicAdd(&h[d < 255 ? d : 255], 1);
    }
    __syncthreads();
    if (h[t]) cur[t] = atomicAdd(&goff[t], h[t]);
    __syncthreads();
    for (int n = n0 + t; n < n1; n += 256) {
        int d = row_ptr[n + 1] - row_ptr[n];
        d = d < 255 ? d : 255;
        int pos = atomicAdd(&cur[d], 1);
        perm[pos] = n;
    }
}

// ---------------- propagation: u_out[i] = scale[i] * (u[i] + sum_j u[j]) ----------------
// Group-per-node (8 nodes/wave), processed in DEGREE-SORTED order via perm so
// the wave-uniform round count R = max(deg over 8 nodes) ~= deg (was ~1.8x
// deg with unsorted waves). R is wave-uniform -> the guards below are uniform
// branches that skip dead gather-issues/accumulates in the final iteration.

__device__ __forceinline__ void acc16w(float4 hv, float w, float* acc) {
    __half2* hp = (__half2*)&hv;
    #pragma unroll
    for (int i2 = 0; i2 < 4; ++i2) {
        float2 f = __half22float2(hp[i2]);
        acc[2 * i2]     = fmaf(w, f.x, acc[2 * i2]);
        acc[2 * i2 + 1] = fmaf(w, f.y, acc[2 * i2 + 1]);
    }
}

__global__ void __launch_bounds__(256, 8)
prop_kernel(const __half* __restrict__ hin, __half* __restrict__ hout,
            const int* __restrict__ row_ptr, const int* __restrict__ adj,
            const float* __restrict__ scale, const int* __restrict__ perm,
            int N, int E) {
    int wid  = (blockIdx.x * blockDim.x + threadIdx.x) >> 6;
    int lane = threadIdx.x & 63;
    int g    = lane >> 3;
    int q    = lane & 7;
    int g8   = g << 3;
    int nb   = wid << 3;
    if (nb >= N) return;
    int  slot  = nb + g;
    bool valid = slot < N;
    int  node  = perm[valid ? slot : 0];
    int rp0 = row_ptr[node];
    int rp1 = row_ptr[node + 1];
    int cnt = valid ? (rp1 - rp0) : 0;

    // wave-uniform round count = max degree over the 8 groups (sorted => tight)
    int R = cnt;
    R = max(R, __shfl_xor(R, 8, 64));
    R = max(R, __shfl_xor(R, 16, 64));
    R = max(R, __shfl_xor(R, 32, 64));

    const float4* hin16 = (const float4*)hin;
    float4 selfv = hin16[(size_t)node * 8 + q];   // per-group 128B read

    int eCur = adj[rp0 + q];          // edges 0..7 of this group's node
    int eNxt = 0;
    float4 gA0, gA1, gA2, gA3, gB0, gB1, gB2, gB3;
    int j0, j1, j2, j3;
    if (R > 0) {                      // uniform
        j0 = __shfl(eCur, g8 + 0, 64); j0 = (0 < cnt) ? j0 : 0;
        j1 = __shfl(eCur, g8 + 1, 64); j1 = (1 < cnt) ? j1 : 0;
        j2 = __shfl(eCur, g8 + 2, 64); j2 = (2 < cnt) ? j2 : 0;
        j3 = __shfl(eCur, g8 + 3, 64); j3 = (3 < cnt) ? j3 : 0;
        gA0 = hin16[(size_t)j0 * 8 + q];
        gA1 = hin16[(size_t)j1 * 8 + q];
        gA2 = hin16[(size_t)j2 * 8 + q];
        gA3 = hin16[(size_t)j3 * 8 + q];
        if (R > 8) eNxt = adj[rp0 + 8 + q];
    }

    float acc[8] = {0.f, 0.f, 0.f, 0.f, 0.f, 0.f, 0.f, 0.f};
    acc16w(selfv, 1.f, acc);

    for (int r = 0; r < R; r += 8) {
        bool hb = (r + 4 < R);        // uniform: gB rounds needed
        bool hn = (r + 8 < R);        // uniform: another iteration follows
        int t;
        if (hb) {                     // issue gB <- rounds r+4..r+7
            t = r + 4; j0 = __shfl(eCur, g8 + (t & 7), 64); j0 = (t < cnt) ? j0 : 0;
            t = r + 5; j1 = __shfl(eCur, g8 + (t & 7), 64); j1 = (t < cnt) ? j1 : 0;
            t = r + 6; j2 = __shfl(eCur, g8 + (t & 7), 64); j2 = (t < cnt) ? j2 : 0;
            t = r + 7; j3 = __shfl(eCur, g8 + (t & 7), 64); j3 = (t < cnt) ? j3 : 0;
            gB0 = hin16[(size_t)j0 * 8 + q];
            gB1 = hin16[(size_t)j1 * 8 + q];
            gB2 = hin16[(size_t)j2 * 8 + q];
            gB3 = hin16[(size_t)j3 * 8 + q];
        }
        float w;
        w = (r + 0 < cnt) ? 1.f : 0.f; acc16w(gA0, w, acc);
        w = (r + 1 < cnt) ? 1.f : 0.f; acc16w(gA1, w, acc);
        w = (r + 2 < cnt) ? 1.f : 0.f; acc16w(gA2, w, acc);
        w = (r + 3 < cnt) ? 1.f : 0.f; acc16w(gA3, w, acc);
        if (hn) {                     // issue gA <- rounds r+8..r+11
            t = r + 8;  j0 = __shfl(eNxt, g8 + (t & 7), 64); j0 = (t < cnt) ? j0 : 0;
            t = r + 9;  j1 = __shfl(eNxt, g8 + (t & 7), 64); j1 = (t < cnt) ? j1 : 0;
            t = r + 10; j2 = __shfl(eNxt, g8 + (t & 7), 64); j2 = (t < cnt) ? j2 : 0;
            t = r + 11; j3 = __shfl(eNxt, g8 + (t & 7), 64); j3 = (t < cnt) ? j3 : 0;
            gA0 = hin16[(size_t)j0 * 8 + q];
            gA1 = hin16[(size_t)j1 * 8 + q];
            gA2 = hin16[(size_t)j2 * 8 + q];
            gA3 = hin16[(size_t)j3 * 8 + q];
        }
        if (hb) {
            w = (r + 4 < cnt) ? 1.f : 0.f; acc16w(gB0, w, acc);
            w = (r + 5 < cnt) ? 1.f : 0.f; acc16w(gB1, w, acc);
            w = (r + 6 < cnt) ? 1.f : 0.f; acc16w(gB2, w, acc);
            w = (r + 7 < cnt) ? 1.f : 0.f; acc16w(gB3, w, acc);
        }
        if (hn) {                     // roll batch regs (rounds r+16..r+23)
            eCur = eNxt;
            int ao = rp0 + r + 16;
            ao = (ao > E + 96) ? (E + 96) : ao;   // stay inside the +128 pad
            eNxt = adj[ao + q];
        }
    }

    if (valid) {
        float sc = scale[node];
        float4 o;
        __half2* op = (__half2*)&o;
        op[0] = __float22half2_rn(make_float2(sc * acc[0], sc * acc[1]));
        op[1] = __float22half2_rn(make_float2(sc * acc[2], sc * acc[3]));
        op[2] = __float22half2_rn(make_float2(sc * acc[4], sc * acc[5]));
        op[3] = __float22half2_rn(make_float2(sc * acc[6], sc * acc[7]));
        ((float4*)hout)[(size_t)node * 8 + q] = o;   // per-group 128B store
    }
}

// ---------------- final: out = 2x + h @ W^T + b - x_pre ----------------
__global__ void __launch_bounds__(256, 2)
final_kernel(const __half* __restrict__ h, const float* __restrict__ x,
             const float* __restrict__ xp, const float* __restrict__ W,
             const float* __restrict__ b, float* __restrict__ out, int N) {
    __shared__ __align__(16) float ht[64 * 68];
    __shared__ __align__(16) float Wt[64 * 68];
    int t = threadIdx.x;
    int nodeBase = blockIdx.x * 64;

    for (int i = t; i < 1024; i += 256) {
        int c  = i >> 4;
        int k4 = i & 15;
        float4 w4 = ((const float4*)W)[i];
        Wt[(k4 * 4 + 0) * 68 + c] = w4.x;
        Wt[(k4 * 4 + 1) * 68 + c] = w4.y;
        Wt[(k4 * 4 + 2) * 68 + c] = w4.z;
        Wt[(k4 * 4 + 3) * 68 + c] = w4.w;
    }
    for (int i = t; i < 512; i += 256) {
        int n  = i >> 3;
        int k8 = i & 7;
        int node = nodeBase + n;
        float4 hv = (node < N) ? ((const float4*)h)[node * 8 + k8]
                               : make_float4(0.f, 0.f, 0.f, 0.f);
        __half2* hp = (__half2*)&hv;
        #pragma unroll
        for (int j = 0; j < 4; ++j) {
            float2 f = __half22float2(hp[j]);
            ht[(k8 * 8 + 2 * j)     * 68 + n] = f.x;
            ht[(k8 * 8 + 2 * j + 1) * 68 + n] = f.y;
        }
    }
    __syncthreads();

    int r0 = (t >> 4) * 4;
    int c0 = (t & 15) * 4;
    float acc[4][4] = {};
    #pragma unroll 8
    for (int k = 0; k < 64; ++k) {
        float4 hv = *(const float4*)&ht[k * 68 + r0];
        float4 wv = *(const float4*)&Wt[k * 68 + c0];
        acc[0][0] = fmaf(hv.x, wv.x, acc[0][0]);
        acc[0][1] = fmaf(hv.x, wv.y, acc[0][1]);
        acc[0][2] = fmaf(hv.x, wv.z, acc[0][2]);
        acc[0][3] = fmaf(hv.x, wv.w, acc[0][3]);
        acc[1][0] = fmaf(hv.y, wv.x, acc[1][0]);
        acc[1][1] = fmaf(hv.y, wv.y, acc[1][1]);
        acc[1][2] = fmaf(hv.y, wv.z, acc[1][2]);
        acc[1][3] = fmaf(hv.y, wv.w, acc[1][3]);
        acc[2][0] = fmaf(hv.z, wv.x, acc[2][0]);
        acc[2][1] = fmaf(hv.z, wv.y, acc[2][1]);
        acc[2][2] = fmaf(hv.z, wv.z, acc[2][2]);
        acc[2][3] = fmaf(hv.z, wv.w, acc[2][3]);
        acc[3][0] = fmaf(hv.w, wv.x, acc[3][0]);
        acc[3][1] = fmaf(hv.w, wv.y, acc[3][1]);
        acc[3][2] = fmaf(hv.w, wv.z, acc[3][2]);
        acc[3][3] = fmaf(hv.w, wv.w, acc[3][3]);
    }

    float4 bv = *(const float4*)&b[c0];
    #pragma unroll
    for (int i = 0; i < 4; ++i) {
        int node = nodeBase + r0 + i;
        if (node >= N) continue;
        int base = node * 64 + c0;
        float4 xv = *(const float4*)&x[base];
        float4 pv = *(const float4*)&xp[base];
        float4 o;
        o.x = fmaf(2.f, xv.x, acc[i][0] + bv.x) - pv.x;
        o.y = fmaf(2.f, xv.y, acc[i][1] + bv.y) - pv.y;
        o.z = fmaf(2.f, xv.z, acc[i][2] + bv.z) - pv.z;
        o.w = fmaf(2.f, xv.w, acc[i][3] + bv.w) - pv.w;
        *(float4*)&out[base] = o;
    }
}

extern "C" void kernel_launch(void* const* d_in, const int* in_sizes, int n_in,
                              void* d_out, int out_size, void* d_ws, size_t ws_size,
                              hipStream_t stream) {
    const float* x    = (const float*)d_in[0];
    const float* xpre = (const float*)d_in[1];
    const int*   ei   = (const int*)d_in[2];
    const float* W    = (const float*)d_in[3];
    const float* b    = (const float*)d_in[4];
    float* out = (float*)d_out;

    const int N = in_sizes[0] / CCH;
    const int E = in_sizes[2] / 2;
    const int* src = ei;
    const int* dst = ei + E;

    const int B     = (N + BKT - 1) / BKT;       // buckets
    const int M     = B * NBLK;                  // count-matrix size
    const int chunk = (E + NBLK - 1) / NBLK;
    const int NB2   = (M + 1023) / 1024;         // scan1 blocks
    const int chkP  = (N + PB - 1) / PB;         // perm-scatter chunk

    // workspace partition (256B aligned)
    char* p = (char*)d_ws;
    auto alloc = [&](size_t bytes) -> char* {
        char* r = p;
        p += (bytes + 255) & ~(size_t)255;
        return r;
    };
    int*      cntmat  = (int*)alloc((size_t)M * 4);
    int*      part    = (int*)alloc((size_t)M * 4);
    int*      bsum    = (int*)alloc((size_t)NB2 * 4);
    unsigned* brec    = (unsigned*)alloc((size_t)E * 4);
    int*      adj     = (int*)alloc(((size_t)E + 128) * 4);  // +128 pad for batch prefetch
    int*      row_ptr = (int*)alloc(((size_t)N + 1) * 4);
    float*    dinv    = (float*)alloc((size_t)N * 4);
    float*    dinv2   = (float*)alloc((size_t)N * 4);
    int*      ghist   = (int*)alloc(256 * 4);
    int*      perm    = (int*)alloc((size_t)N * 4);
    __half*   xh      = (__half*)alloc((size_t)N * CCH * 2);
    __half*   g0      = (__half*)alloc((size_t)N * CCH * 2);
    __half*   g1      = (__half*)alloc((size_t)N * CCH * 2);

    countA<<<NBLK, 256, 0, stream>>>(dst, cntmat, ghist, E, chunk, B);
    scan1 <<<NB2, 256, 0, stream>>>(cntmat, part, bsum, M);
    scan2 <<<1, 256, 0, stream>>>(bsum, NB2);
    partA <<<NBLK, 256, 0, stream>>>(src, dst, part, bsum, brec, E, chunk, B);
    buildB<<<B, 256, 0, stream>>>(brec, part, bsum, row_ptr, adj, dinv, dinv2,
                                  x, xh, ghist, N, B, E);
    permScan   <<<1, 256, 0, stream>>>(ghist);
    permScatter<<<PB, 256, 0, stream>>>(row_ptr, ghist, perm, N, chkP);

    const int nwave = (N + 7) / 8;               // 8 nodes per wave
    const int pgrid = (nwave + 3) / 4;           // 4 waves per 256-thread block
    prop_kernel<<<pgrid, 256, 0, stream>>>(xh, g0, row_ptr, adj, dinv2, perm, N, E); // hop 1
    prop_kernel<<<pgrid, 256, 0, stream>>>(g0, g1, row_ptr, adj, dinv2, perm, N, E); // hop 2
    prop_kernel<<<pgrid, 256, 0, stream>>>(g1, g0, row_ptr, adj, dinv2, perm, N, E); // hop 3
    prop_kernel<<<pgrid, 256, 0, stream>>>(g0, g1, row_ptr, adj, dinv,  perm, N, E); // hop 4 -> g1=h

    final_kernel<<<(N + 63) / 64, 256, 0, stream>>>(g1, x, xpre, W, b, out, N);
}

// Round 3
// 336.163 us; speedup vs baseline: 1.3030x; 1.3030x over previous
//
#include <hip/hip_runtime.h>
#include <hip/hip_fp16.h>

#define CCH 64
#define NBLK 128        // phase-A partition blocks
#define BKT  256        // nodes per bucket

// ---------------- Phase A: partitioned counting sort of edges by dst ----------------

__global__ void countA(const int* __restrict__ dst, int* __restrict__ cntmat,
                       int E, int chunk, int B) {
    __shared__ int h[512];
    int t = threadIdx.x, blk = blockIdx.x;
    for (int i = t; i < B; i += 256) h[i] = 0;
    __syncthreads();
    int e0 = blk * chunk, e1 = min(e0 + chunk, E);
    for (int e = e0 + t; e < e1; e += 256) atomicAdd(&h[dst[e] >> 8], 1);
    __syncthreads();
    for (int i = t; i < B; i += 256) cntmat[i * NBLK + blk] = h[i];
}

// Two-level exclusive scan (1024 elems / block)
__global__ void scan1(const int* __restrict__ cnt, int* __restrict__ part,
                      int* __restrict__ bsum, int N) {
    __shared__ int s[256];
    int t = threadIdx.x;
    int base = blockIdx.x * 1024 + t * 4;
    int v0 = (base + 0 < N) ? cnt[base + 0] : 0;
    int v1 = (base + 1 < N) ? cnt[base + 1] : 0;
    int v2 = (base + 2 < N) ? cnt[base + 2] : 0;
    int v3 = (base + 3 < N) ? cnt[base + 3] : 0;
    s[t] = v0 + v1 + v2 + v3;
    __syncthreads();
    for (int off = 1; off < 256; off <<= 1) {
        int xx = (t >= off) ? s[t - off] : 0;
        __syncthreads();
        s[t] += xx;
        __syncthreads();
    }
    int excl = (t == 0) ? 0 : s[t - 1];
    if (t == 255) bsum[blockIdx.x] = s[255];
    if (base + 0 < N) part[base + 0] = excl;
    if (base + 1 < N) part[base + 1] = excl + v0;
    if (base + 2 < N) part[base + 2] = excl + v0 + v1;
    if (base + 3 < N) part[base + 3] = excl + v0 + v1 + v2;
}

__global__ void scan2(int* __restrict__ bsum, int NB) {
    __shared__ int s[256];
    int t = threadIdx.x;
    int base = t * 4;
    int v0 = (base + 0 < NB) ? bsum[base + 0] : 0;
    int v1 = (base + 1 < NB) ? bsum[base + 1] : 0;
    int v2 = (base + 2 < NB) ? bsum[base + 2] : 0;
    int v3 = (base + 3 < NB) ? bsum[base + 3] : 0;
    s[t] = v0 + v1 + v2 + v3;
    __syncthreads();
    for (int off = 1; off < 256; off <<= 1) {
        int xx = (t >= off) ? s[t - off] : 0;
        __syncthreads();
        s[t] += xx;
        __syncthreads();
    }
    int excl = (t == 0) ? 0 : s[t - 1];
    if (base + 0 < NB) bsum[base + 0] = excl;
    if (base + 1 < NB) bsum[base + 1] = excl + v0;
    if (base + 2 < NB) bsum[base + 2] = excl + v0 + v1;
    if (base + 3 < NB) bsum[base + 3] = excl + v0 + v1 + v2;
}

// partition: write (src<<8 | dst&255) into per-(block,bucket) exclusive ranges.
__global__ void partA(const int* __restrict__ src, const int* __restrict__ dst,
                      const int* __restrict__ part, const int* __restrict__ bsum,
                      unsigned* __restrict__ brec, int E, int chunk, int B) {
    __shared__ int cur[512];
    int t = threadIdx.x, blk = blockIdx.x;
    for (int i = t; i < B; i += 256) {
        int idx = i * NBLK + blk;
        cur[i] = part[idx] + bsum[idx >> 10];
    }
    __syncthreads();
    int e0 = blk * chunk, e1 = min(e0 + chunk, E);
    for (int e = e0 + t; e < e1; e += 256) {
        int s = src[e], d = dst[e];
        int pos = atomicAdd(&cur[d >> 8], 1);
        brec[pos] = ((unsigned)s << 8) | (unsigned)(d & 255);
    }
}

// ---------------- Phase B: per-bucket CSR finalize + u0 = fp16(dinv*x) ----------------
__global__ void buildB(const unsigned* __restrict__ brec, const int* __restrict__ part,
                       const int* __restrict__ bsum, int* __restrict__ row_ptr,
                       int* __restrict__ adj, float* __restrict__ dinv,
                       float* __restrict__ dinv2, const float* __restrict__ x,
                       __half* __restrict__ xh, int N, int B, int E) {
    __shared__ int hist[256];
    __shared__ int scanbuf[256];
    __shared__ int cursor[256];
    __shared__ float sdinv[256];
    int t = threadIdx.x, k = blockIdx.x;
    int i0 = k * NBLK;
    int base = part[i0] + bsum[i0 >> 10];
    int nextb;
    if (k + 1 < B) {
        int i1 = (k + 1) * NBLK;
        nextb = part[i1] + bsum[i1 >> 10];
    } else {
        nextb = E;
    }
    hist[t] = 0;
    __syncthreads();
    for (int i = base + t; i < nextb; i += 256) atomicAdd(&hist[brec[i] & 255u], 1);
    __syncthreads();
    int v = hist[t];
    scanbuf[t] = v;
    __syncthreads();
    for (int o = 1; o < 256; o <<= 1) {
        int xx = (t >= o) ? scanbuf[t - o] : 0;
        __syncthreads();
        scanbuf[t] += xx;
        __syncthreads();
    }
    int excl = scanbuf[t] - v;
    int node = k * 256 + t;
    float di = 0.f;
    if (node < N) {
        int p = base + excl;
        row_ptr[node] = p;
        cursor[t] = p;
        float dp1 = (float)v + 1.0f;          // degree incl. self-loop
        di = rsqrtf(dp1);
        dinv[node]  = di;
        dinv2[node] = 1.0f / dp1;
    }
    sdinv[t] = di;
    if (k == 0 && t == 0) row_ptr[N] = E;
    __syncthreads();
    for (int i = base + t; i < nextb; i += 256) {
        unsigned r = brec[i];
        int pos = atomicAdd(&cursor[r & 255u], 1);
        adj[pos] = (int)(r >> 8);
    }
    // fused tohalf for this bucket (coalesced; overlaps scatter latency)
    int nodeBase = k * 256;
    for (int i = t; i < 2048; i += 256) {
        int nl = i >> 3;
        int node2 = nodeBase + nl;
        if (node2 < N) {
            float d = sdinv[nl];
            size_t baseE = (size_t)node2 * 64 + (size_t)(i & 7) * 8;
            float4 a = *(const float4*)&x[baseE];
            float4 c = *(const float4*)&x[baseE + 4];
            float4 o;
            __half2* op = (__half2*)&o;
            op[0] = __float22half2_rn(make_float2(d * a.x, d * a.y));
            op[1] = __float22half2_rn(make_float2(d * a.z, d * a.w));
            op[2] = __float22half2_rn(make_float2(d * c.x, d * c.y));
            op[3] = __float22half2_rn(make_float2(d * c.z, d * c.w));
            *(float4*)&xh[baseE] = o;
        }
    }
}

// ---------------- propagation: u_out[i] = scale[i] * (u[i] + sum_j u[j]) ----------------
// Group-per-node, 8 nodes/wave, CONTIGUOUS node blocks (R2 lesson: degree-perm
// scatters self-read/store -> 12x write amplification; never scatter rows).
// R2 counters: latency-bound (VALUBusy 10%, BW 4/6.3 TB/s) -> this round each
// row gather is SPLIT into two 64B float2 gathers: identical byte traffic,
// identical bank VGPR footprint, but 2x requests in flight per wave (8 vs 4
// during every accumulate phase).

__device__ __forceinline__ void acc8w(float2 hv, float w, float* acc) {
    __half2* hp = (__half2*)&hv;     // 4 halves
    float2 f0 = __half22float2(hp[0]);
    float2 f1 = __half22float2(hp[1]);
    acc[0] = fmaf(w, f0.x, acc[0]);
    acc[1] = fmaf(w, f0.y, acc[1]);
    acc[2] = fmaf(w, f1.x, acc[2]);
    acc[3] = fmaf(w, f1.y, acc[3]);
}

__global__ void __launch_bounds__(256, 6)
prop_kernel(const __half* __restrict__ hin, __half* __restrict__ hout,
            const int* __restrict__ row_ptr, const int* __restrict__ adj,
            const float* __restrict__ scale, int N, int E) {
    int wid  = (blockIdx.x * blockDim.x + threadIdx.x) >> 6;
    int lane = threadIdx.x & 63;
    int g    = lane >> 3;
    int q    = lane & 7;
    int g8   = g << 3;
    int nb   = wid << 3;
    if (nb >= N) return;
    int  node  = nb + g;
    bool valid = node < N;
    int  nodeC = valid ? node : (N - 1);
    int rp0 = row_ptr[nodeC];
    int rp1 = row_ptr[nodeC + 1];
    int cnt = valid ? (rp1 - rp0) : 0;

    // wave-uniform round count = max degree over the 8 groups
    int R = cnt;
    R = max(R, __shfl_xor(R, 8, 64));
    R = max(R, __shfl_xor(R, 16, 64));
    R = max(R, __shfl_xor(R, 32, 64));

    const float2* hin2 = (const float2*)hin;   // row j: lo = j*16+q, hi = j*16+8+q
    size_t nrow = (size_t)nodeC * 16;
    float2 selfLo = hin2[nrow + q];            // coalesced 1KB wave read (2 instrs)
    float2 selfHi = hin2[nrow + 8 + q];

    int eCur = adj[rp0 + q];          // edges 0..7 of this group's node
    int eNxt = 0;
    float2 gAl0, gAl1, gAl2, gAl3, gAh0, gAh1, gAh2, gAh3;
    float2 gBl0, gBl1, gBl2, gBl3, gBh0, gBh1, gBh2, gBh3;
    int j0, j1, j2, j3;
    if (R > 0) {                      // uniform
        j0 = __shfl(eCur, g8 + 0, 64); j0 = (0 < cnt) ? j0 : 0;
        j1 = __shfl(eCur, g8 + 1, 64); j1 = (1 < cnt) ? j1 : 0;
        j2 = __shfl(eCur, g8 + 2, 64); j2 = (2 < cnt) ? j2 : 0;
        j3 = __shfl(eCur, g8 + 3, 64); j3 = (3 < cnt) ? j3 : 0;
        gAl0 = hin2[(size_t)j0 * 16 + q];     gAh0 = hin2[(size_t)j0 * 16 + 8 + q];
        gAl1 = hin2[(size_t)j1 * 16 + q];     gAh1 = hin2[(size_t)j1 * 16 + 8 + q];
        gAl2 = hin2[(size_t)j2 * 16 + q];     gAh2 = hin2[(size_t)j2 * 16 + 8 + q];
        gAl3 = hin2[(size_t)j3 * 16 + q];     gAh3 = hin2[(size_t)j3 * 16 + 8 + q];
        if (R > 8) eNxt = adj[rp0 + 8 + q];
    }

    float acc[8] = {0.f, 0.f, 0.f, 0.f, 0.f, 0.f, 0.f, 0.f};
    acc8w(selfLo, 1.f, acc);
    acc8w(selfHi, 1.f, acc + 4);

    for (int r = 0; r < R; r += 8) {
        bool hb = (r + 4 < R);        // uniform: gB rounds needed
        bool hn = (r + 8 < R);        // uniform: another iteration follows
        int t;
        if (hb) {                     // issue gB <- rounds r+4..r+7 (8 requests)
            t = r + 4; j0 = __shfl(eCur, g8 + (t & 7), 64); j0 = (t < cnt) ? j0 : 0;
            t = r + 5; j1 = __shfl(eCur, g8 + (t & 7), 64); j1 = (t < cnt) ? j1 : 0;
            t = r + 6; j2 = __shfl(eCur, g8 + (t & 7), 64); j2 = (t < cnt) ? j2 : 0;
            t = r + 7; j3 = __shfl(eCur, g8 + (t & 7), 64); j3 = (t < cnt) ? j3 : 0;
            gBl0 = hin2[(size_t)j0 * 16 + q]; gBh0 = hin2[(size_t)j0 * 16 + 8 + q];
            gBl1 = hin2[(size_t)j1 * 16 + q]; gBh1 = hin2[(size_t)j1 * 16 + 8 + q];
            gBl2 = hin2[(size_t)j2 * 16 + q]; gBh2 = hin2[(size_t)j2 * 16 + 8 + q];
            gBl3 = hin2[(size_t)j3 * 16 + q]; gBh3 = hin2[(size_t)j3 * 16 + 8 + q];
        }
        float w;
        w = (r + 0 < cnt) ? 1.f : 0.f; acc8w(gAl0, w, acc); acc8w(gAh0, w, acc + 4);
        w = (r + 1 < cnt) ? 1.f : 0.f; acc8w(gAl1, w, acc); acc8w(gAh1, w, acc + 4);
        w = (r + 2 < cnt) ? 1.f : 0.f; acc8w(gAl2, w, acc); acc8w(gAh2, w, acc + 4);
        w = (r + 3 < cnt) ? 1.f : 0.f; acc8w(gAl3, w, acc); acc8w(gAh3, w, acc + 4);
        if (hn) {                     // issue gA <- rounds r+8..r+11
            t = r + 8;  j0 = __shfl(eNxt, g8 + (t & 7), 64); j0 = (t < cnt) ? j0 : 0;
            t = r + 9;  j1 = __shfl(eNxt, g8 + (t & 7), 64); j1 = (t < cnt) ? j1 : 0;
            t = r + 10; j2 = __shfl(eNxt, g8 + (t & 7), 64); j2 = (t < cnt) ? j2 : 0;
            t = r + 11; j3 = __shfl(eNxt, g8 + (t & 7), 64); j3 = (t < cnt) ? j3 : 0;
            gAl0 = hin2[(size_t)j0 * 16 + q]; gAh0 = hin2[(size_t)j0 * 16 + 8 + q];
            gAl1 = hin2[(size_t)j1 * 16 + q]; gAh1 = hin2[(size_t)j1 * 16 + 8 + q];
            gAl2 = hin2[(size_t)j2 * 16 + q]; gAh2 = hin2[(size_t)j2 * 16 + 8 + q];
            gAl3 = hin2[(size_t)j3 * 16 + q]; gAh3 = hin2[(size_t)j3 * 16 + 8 + q];
        }
        if (hb) {
            w = (r + 4 < cnt) ? 1.f : 0.f; acc8w(gBl0, w, acc); acc8w(gBh0, w, acc + 4);
            w = (r + 5 < cnt) ? 1.f : 0.f; acc8w(gBl1, w, acc); acc8w(gBh1, w, acc + 4);
            w = (r + 6 < cnt) ? 1.f : 0.f; acc8w(gBl2, w, acc); acc8w(gBh2, w, acc + 4);
            w = (r + 7 < cnt) ? 1.f : 0.f; acc8w(gBl3, w, acc); acc8w(gBh3, w, acc + 4);
        }
        if (hn) {                     // roll batch regs (rounds r+16..r+23)
            eCur = eNxt;
            int ao = rp0 + r + 16;
            ao = (ao > E + 96) ? (E + 96) : ao;   // stay inside the +128 pad
            eNxt = adj[ao + q];
        }
    }

    if (valid) {
        float sc = scale[nodeC];
        union { float2 f; __half2 h[2]; } olo, ohi;
        olo.h[0] = __float22half2_rn(make_float2(sc * acc[0], sc * acc[1]));
        olo.h[1] = __float22half2_rn(make_float2(sc * acc[2], sc * acc[3]));
        ohi.h[0] = __float22half2_rn(make_float2(sc * acc[4], sc * acc[5]));
        ohi.h[1] = __float22half2_rn(make_float2(sc * acc[6], sc * acc[7]));
        float2* out2 = (float2*)hout;
        out2[nrow + q]     = olo.f;   // coalesced 1KB wave store (2 instrs)
        out2[nrow + 8 + q] = ohi.f;
    }
}

// ---------------- final: out = 2x + h @ W^T + b - x_pre ----------------
__global__ void __launch_bounds__(256, 2)
final_kernel(const __half* __restrict__ h, const float* __restrict__ x,
             const float* __restrict__ xp, const float* __restrict__ W,
             const float* __restrict__ b, float* __restrict__ out, int N) {
    __shared__ __align__(16) float ht[64 * 68];
    __shared__ __align__(16) float Wt[64 * 68];
    int t = threadIdx.x;
    int nodeBase = blockIdx.x * 64;

    for (int i = t; i < 1024; i += 256) {
        int c  = i >> 4;
        int k4 = i & 15;
        float4 w4 = ((const float4*)W)[i];
        Wt[(k4 * 4 + 0) * 68 + c] = w4.x;
        Wt[(k4 * 4 + 1) * 68 + c] = w4.y;
        Wt[(k4 * 4 + 2) * 68 + c] = w4.z;
        Wt[(k4 * 4 + 3) * 68 + c] = w4.w;
    }
    for (int i = t; i < 512; i += 256) {
        int n  = i >> 3;
        int k8 = i & 7;
        int node = nodeBase + n;
        float4 hv = (node < N) ? ((const float4*)h)[node * 8 + k8]
                               : make_float4(0.f, 0.f, 0.f, 0.f);
        __half2* hp = (__half2*)&hv;
        #pragma unroll
        for (int j = 0; j < 4; ++j) {
            float2 f = __half22float2(hp[j]);
            ht[(k8 * 8 + 2 * j)     * 68 + n] = f.x;
            ht[(k8 * 8 + 2 * j + 1) * 68 + n] = f.y;
        }
    }
    __syncthreads();

    int r0 = (t >> 4) * 4;
    int c0 = (t & 15) * 4;
    float acc[4][4] = {};
    #pragma unroll 8
    for (int k = 0; k < 64; ++k) {
        float4 hv = *(const float4*)&ht[k * 68 + r0];
        float4 wv = *(const float4*)&Wt[k * 68 + c0];
        acc[0][0] = fmaf(hv.x, wv.x, acc[0][0]);
        acc[0][1] = fmaf(hv.x, wv.y, acc[0][1]);
        acc[0][2] = fmaf(hv.x, wv.z, acc[0][2]);
        acc[0][3] = fmaf(hv.x, wv.w, acc[0][3]);
        acc[1][0] = fmaf(hv.y, wv.x, acc[1][0]);
        acc[1][1] = fmaf(hv.y, wv.y, acc[1][1]);
        acc[1][2] = fmaf(hv.y, wv.z, acc[1][2]);
        acc[1][3] = fmaf(hv.y, wv.w, acc[1][3]);
        acc[2][0] = fmaf(hv.z, wv.x, acc[2][0]);
        acc[2][1] = fmaf(hv.z, wv.y, acc[2][1]);
        acc[2][2] = fmaf(hv.z, wv.z, acc[2][2]);
        acc[2][3] = fmaf(hv.z, wv.w, acc[2][3]);
        acc[3][0] = fmaf(hv.w, wv.x, acc[3][0]);
        acc[3][1] = fmaf(hv.w, wv.y, acc[3][1]);
        acc[3][2] = fmaf(hv.w, wv.z, acc[3][2]);
        acc[3][3] = fmaf(hv.w, wv.w, acc[3][3]);
    }

    float4 bv = *(const float4*)&b[c0];
    #pragma unroll
    for (int i = 0; i < 4; ++i) {
        int node = nodeBase + r0 + i;
        if (node >= N) continue;
        int base = node * 64 + c0;
        float4 xv = *(const float4*)&x[base];
        float4 pv = *(const float4*)&xp[base];
        float4 o;
        o.x = fmaf(2.f, xv.x, acc[i][0] + bv.x) - pv.x;
        o.y = fmaf(2.f, xv.y, acc[i][1] + bv.y) - pv.y;
        o.z = fmaf(2.f, xv.z, acc[i][2] + bv.z) - pv.z;
        o.w = fmaf(2.f, xv.w, acc[i][3] + bv.w) - pv.w;
        *(float4*)&out[base] = o;
    }
}

extern "C" void kernel_launch(void* const* d_in, const int* in_sizes, int n_in,
                              void* d_out, int out_size, void* d_ws, size_t ws_size,
                              hipStream_t stream) {
    const float* x    = (const float*)d_in[0];
    const float* xpre = (const float*)d_in[1];
    const int*   ei   = (const int*)d_in[2];
    const float* W    = (const float*)d_in[3];
    const float* b    = (const float*)d_in[4];
    float* out = (float*)d_out;

    const int N = in_sizes[0] / CCH;
    const int E = in_sizes[2] / 2;
    const int* src = ei;
    const int* dst = ei + E;

    const int B     = (N + BKT - 1) / BKT;       // buckets
    const int M     = B * NBLK;                  // count-matrix size
    const int chunk = (E + NBLK - 1) / NBLK;
    const int NB2   = (M + 1023) / 1024;         // scan1 blocks

    // workspace partition (256B aligned)
    char* p = (char*)d_ws;
    auto alloc = [&](size_t bytes) -> char* {
        char* r = p;
        p += (bytes + 255) & ~(size_t)255;
        return r;
    };
    int*      cntmat  = (int*)alloc((size_t)M * 4);
    int*      part    = (int*)alloc((size_t)M * 4);
    int*      bsum    = (int*)alloc((size_t)NB2 * 4);
    unsigned* brec    = (unsigned*)alloc((size_t)E * 4);
    int*      adj     = (int*)alloc(((size_t)E + 128) * 4);  // +128 pad for batch prefetch
    int*      row_ptr = (int*)alloc(((size_t)N + 1) * 4);
    float*    dinv    = (float*)alloc((size_t)N * 4);
    float*    dinv2   = (float*)alloc((size_t)N * 4);
    __half*   xh      = (__half*)alloc((size_t)N * CCH * 2);
    __half*   g0      = (__half*)alloc((size_t)N * CCH * 2);
    __half*   g1      = (__half*)alloc((size_t)N * CCH * 2);

    countA<<<NBLK, 256, 0, stream>>>(dst, cntmat, E, chunk, B);
    scan1 <<<NB2, 256, 0, stream>>>(cntmat, part, bsum, M);
    scan2 <<<1, 256, 0, stream>>>(bsum, NB2);
    partA <<<NBLK, 256, 0, stream>>>(src, dst, part, bsum, brec, E, chunk, B);
    buildB<<<B, 256, 0, stream>>>(brec, part, bsum, row_ptr, adj, dinv, dinv2,
                                  x, xh, N, B, E);

    const int nwave = (N + 7) / 8;               // 8 nodes per wave
    const int pgrid = (nwave + 3) / 4;           // 4 waves per 256-thread block
    prop_kernel<<<pgrid, 256, 0, stream>>>(xh, g0, row_ptr, adj, dinv2, N, E); // hop 1
    prop_kernel<<<pgrid, 256, 0, stream>>>(g0, g1, row_ptr, adj, dinv2, N, E); // hop 2
    prop_kernel<<<pgrid, 256, 0, stream>>>(g1, g0, row_ptr, adj, dinv2, N, E); // hop 3
    prop_kernel<<<pgrid, 256, 0, stream>>>(g0, g1, row_ptr, adj, dinv,  N, E); // hop 4 -> g1=h

    final_kernel<<<(N + 63) / 64, 256, 0, stream>>>(g1, x, xpre, W, b, out, N);
}

// Round 5
// 246.846 us; speedup vs baseline: 1.7744x; 1.3618x over previous
//
#include <hip/hip_runtime.h>
#include <hip/hip_fp16.h>

#define CCH 64
#define NBLK 128        // phase-A partition blocks
#define BKT  256        // nodes per bucket

// ---------------- Phase A: partitioned counting sort of edges by dst ----------------

__global__ void countA(const int* __restrict__ dst, int* __restrict__ cntmat,
                       int E, int chunk, int B) {
    __shared__ int h[512];
    int t = threadIdx.x, blk = blockIdx.x;
    for (int i = t; i < B; i += 256) h[i] = 0;
    __syncthreads();
    int e0 = blk * chunk, e1 = min(e0 + chunk, E);
    for (int e = e0 + t; e < e1; e += 256) atomicAdd(&h[dst[e] >> 8], 1);
    __syncthreads();
    for (int i = t; i < B; i += 256) cntmat[i * NBLK + blk] = h[i];
}

// Level-1 scan (1024 elems / block); bsum gets per-block totals (NOT scanned --
// consumers inline-scan it, scan2 kernel eliminated).
__global__ void scan1(const int* __restrict__ cnt, int* __restrict__ part,
                      int* __restrict__ bsum, int N) {
    __shared__ int s[256];
    int t = threadIdx.x;
    int base = blockIdx.x * 1024 + t * 4;
    int v0 = (base + 0 < N) ? cnt[base + 0] : 0;
    int v1 = (base + 1 < N) ? cnt[base + 1] : 0;
    int v2 = (base + 2 < N) ? cnt[base + 2] : 0;
    int v3 = (base + 3 < N) ? cnt[base + 3] : 0;
    s[t] = v0 + v1 + v2 + v3;
    __syncthreads();
    for (int off = 1; off < 256; off <<= 1) {
        int xx = (t >= off) ? s[t - off] : 0;
        __syncthreads();
        s[t] += xx;
        __syncthreads();
    }
    int excl = (t == 0) ? 0 : s[t - 1];
    if (t == 255) bsum[blockIdx.x] = s[255];
    if (base + 0 < N) part[base + 0] = excl;
    if (base + 1 < N) part[base + 1] = excl + v0;
    if (base + 2 < N) part[base + 2] = excl + v0 + v1;
    if (base + 3 < N) part[base + 3] = excl + v0 + v1 + v2;
}

// inline exclusive scan of bsum[0..NB2) into sbs[] (NB2 <= 256). Call with all
// 256 threads; leaves result in sbs, synced.
__device__ __forceinline__ void scan_bsum(const int* __restrict__ bsum, int NB2,
                                          int* sbs, int t) {
    int v = (t < NB2) ? bsum[t] : 0;
    sbs[t] = v;
    __syncthreads();
    for (int o = 1; o < 256; o <<= 1) {
        int xx = (t >= o) ? sbs[t - o] : 0;
        __syncthreads();
        sbs[t] += xx;
        __syncthreads();
    }
    int e = sbs[t] - v;
    __syncthreads();
    sbs[t] = e;
    __syncthreads();
}

// partition: write (src<<8 | dst&255) into per-(block,bucket) exclusive ranges.
__global__ void partA(const int* __restrict__ src, const int* __restrict__ dst,
                      const int* __restrict__ part, const int* __restrict__ bsum,
                      unsigned* __restrict__ brec, int E, int chunk, int B, int NB2) {
    __shared__ int cur[512];
    __shared__ int sbs[256];
    int t = threadIdx.x, blk = blockIdx.x;
    scan_bsum(bsum, NB2, sbs, t);
    for (int i = t; i < B; i += 256) {
        int idx = i * NBLK + blk;
        cur[i] = part[idx] + sbs[idx >> 10];
    }
    __syncthreads();
    int e0 = blk * chunk, e1 = min(e0 + chunk, E);
    for (int e = e0 + t; e < e1; e += 256) {
        int s = src[e], d = dst[e];
        int pos = atomicAdd(&cur[d >> 8], 1);
        brec[pos] = ((unsigned)s << 8) | (unsigned)(d & 255);
    }
}

// ---------------- Phase B: per-bucket CSR finalize + u0 = fp16(dinv*x) ----------------
__global__ void buildB(const unsigned* __restrict__ brec, const int* __restrict__ part,
                       const int* __restrict__ bsum, int* __restrict__ row_ptr,
                       int* __restrict__ adj, float* __restrict__ dinv,
                       float* __restrict__ dinv2, const float* __restrict__ x,
                       __half* __restrict__ xh, int N, int B, int E, int NB2) {
    __shared__ int hist[256];
    __shared__ int scanbuf[256];
    __shared__ int cursor[256];
    __shared__ int sbs[256];
    __shared__ float sdinv[256];
    int t = threadIdx.x, k = blockIdx.x;
    scan_bsum(bsum, NB2, sbs, t);
    int i0 = k * NBLK;
    int base = part[i0] + sbs[i0 >> 10];
    int nextb;
    if (k + 1 < B) {
        int i1 = (k + 1) * NBLK;
        nextb = part[i1] + sbs[i1 >> 10];
    } else {
        nextb = E;
    }
    hist[t] = 0;
    __syncthreads();
    for (int i = base + t; i < nextb; i += 256) atomicAdd(&hist[brec[i] & 255u], 1);
    __syncthreads();
    int v = hist[t];
    scanbuf[t] = v;
    __syncthreads();
    for (int o = 1; o < 256; o <<= 1) {
        int xx = (t >= o) ? scanbuf[t - o] : 0;
        __syncthreads();
        scanbuf[t] += xx;
        __syncthreads();
    }
    int excl = scanbuf[t] - v;
    int node = k * 256 + t;
    float di = 0.f;
    if (node < N) {
        int p = base + excl;
        row_ptr[node] = p;
        cursor[t] = p;
        float dp1 = (float)v + 1.0f;          // degree incl. self-loop
        di = rsqrtf(dp1);
        dinv[node]  = di;
        dinv2[node] = 1.0f / dp1;
    }
    sdinv[t] = di;
    if (k == 0 && t == 0) row_ptr[N] = E;
    __syncthreads();
    for (int i = base + t; i < nextb; i += 256) {
        unsigned r = brec[i];
        int pos = atomicAdd(&cursor[r & 255u], 1);
        adj[pos] = (int)(r >> 8);
    }
    // fused tohalf for this bucket (coalesced; overlaps scatter latency)
    int nodeBase = k * 256;
    for (int i = t; i < 2048; i += 256) {
        int nl = i >> 3;
        int node2 = nodeBase + nl;
        if (node2 < N) {
            float d = sdinv[nl];
            size_t baseE = (size_t)node2 * 64 + (size_t)(i & 7) * 8;
            float4 a = *(const float4*)&x[baseE];
            float4 c = *(const float4*)&x[baseE + 4];
            float4 o;
            __half2* op = (__half2*)&o;
            op[0] = __float22half2_rn(make_float2(d * a.x, d * a.y));
            op[1] = __float22half2_rn(make_float2(d * a.z, d * a.w));
            op[2] = __float22half2_rn(make_float2(d * c.x, d * c.y));
            op[3] = __float22half2_rn(make_float2(d * c.z, d * c.w));
            *(float4*)&xh[baseE] = o;
        }
    }
}

// ---------------- propagation: u_out[i] = scale[i] * (u[i] + sum_j u[j]) ----------------
// Group-per-node, 8 nodes/wave, contiguous node blocks, float4 (128B) gathers
// ONLY (R3 lesson: sub-128B stores amplify writes 5x; keep 128B granularity).
// This is the measured-264.9 R1 body, unmodified.

__device__ __forceinline__ void acc16w(float4 hv, float w, float* acc) {
    __half2* hp = (__half2*)&hv;
    #pragma unroll
    for (int i2 = 0; i2 < 4; ++i2) {
        float2 f = __half22float2(hp[i2]);
        acc[2 * i2]     = fmaf(w, f.x, acc[2 * i2]);
        acc[2 * i2 + 1] = fmaf(w, f.y, acc[2 * i2 + 1]);
    }
}

// shared prop body: accumulates (self + neighbors) into acc[8] for node
// nb+g, channels q*8..q*8+7.
__device__ __forceinline__ void prop_body(const __half* __restrict__ hin,
                                          const int* __restrict__ row_ptr,
                                          const int* __restrict__ adj,
                                          int nodeC, int cnt, int g8, int q,
                                          int E, float* acc) {
    int rp0 = row_ptr[nodeC];

    int R = cnt;
    R = max(R, __shfl_xor(R, 8, 64));
    R = max(R, __shfl_xor(R, 16, 64));
    R = max(R, __shfl_xor(R, 32, 64));

    const float4* hin16 = (const float4*)hin;
    float4 selfv = hin16[(size_t)nodeC * 8 + q];

    int eCur = adj[rp0 + q];          // edges 0..7 of this group's node
    int eNxt = adj[rp0 + 8 + q];      // edges 8..15 (pad-safe)
    int j0 = __shfl(eCur, g8 + 0, 64); j0 = (0 < cnt) ? j0 : 0;
    int j1 = __shfl(eCur, g8 + 1, 64); j1 = (1 < cnt) ? j1 : 0;
    int j2 = __shfl(eCur, g8 + 2, 64); j2 = (2 < cnt) ? j2 : 0;
    int j3 = __shfl(eCur, g8 + 3, 64); j3 = (3 < cnt) ? j3 : 0;
    float4 gA0 = hin16[(size_t)j0 * 8 + q];
    float4 gA1 = hin16[(size_t)j1 * 8 + q];
    float4 gA2 = hin16[(size_t)j2 * 8 + q];
    float4 gA3 = hin16[(size_t)j3 * 8 + q];
    float4 gB0, gB1, gB2, gB3;

    acc16w(selfv, 1.f, acc);

    for (int r = 0; r < R; r += 8) {
        int t;
        t = r + 4; j0 = __shfl(eCur, g8 + (t & 7), 64); j0 = (t < cnt) ? j0 : 0;
        t = r + 5; j1 = __shfl(eCur, g8 + (t & 7), 64); j1 = (t < cnt) ? j1 : 0;
        t = r + 6; j2 = __shfl(eCur, g8 + (t & 7), 64); j2 = (t < cnt) ? j2 : 0;
        t = r + 7; j3 = __shfl(eCur, g8 + (t & 7), 64); j3 = (t < cnt) ? j3 : 0;
        gB0 = hin16[(size_t)j0 * 8 + q];
        gB1 = hin16[(size_t)j1 * 8 + q];
        gB2 = hin16[(size_t)j2 * 8 + q];
        gB3 = hin16[(size_t)j3 * 8 + q];
        float w;
        w = (r + 0 < cnt) ? 1.f : 0.f; acc16w(gA0, w, acc);
        w = (r + 1 < cnt) ? 1.f : 0.f; acc16w(gA1, w, acc);
        w = (r + 2 < cnt) ? 1.f : 0.f; acc16w(gA2, w, acc);
        w = (r + 3 < cnt) ? 1.f : 0.f; acc16w(gA3, w, acc);
        t = r + 8;  j0 = __shfl(eNxt, g8 + (t & 7), 64); j0 = (t < cnt) ? j0 : 0;
        t = r + 9;  j1 = __shfl(eNxt, g8 + (t & 7), 64); j1 = (t < cnt) ? j1 : 0;
        t = r + 10; j2 = __shfl(eNxt, g8 + (t & 7), 64); j2 = (t < cnt) ? j2 : 0;
        t = r + 11; j3 = __shfl(eNxt, g8 + (t & 7), 64); j3 = (t < cnt) ? j3 : 0;
        gA0 = hin16[(size_t)j0 * 8 + q];
        gA1 = hin16[(size_t)j1 * 8 + q];
        gA2 = hin16[(size_t)j2 * 8 + q];
        gA3 = hin16[(size_t)j3 * 8 + q];
        w = (r + 4 < cnt) ? 1.f : 0.f; acc16w(gB0, w, acc);
        w = (r + 5 < cnt) ? 1.f : 0.f; acc16w(gB1, w, acc);
        w = (r + 6 < cnt) ? 1.f : 0.f; acc16w(gB2, w, acc);
        w = (r + 7 < cnt) ? 1.f : 0.f; acc16w(gB3, w, acc);
        eCur = eNxt;
        int ao = rp0 + r + 16;
        ao = (ao > E + 96) ? (E + 96) : ao;   // stay inside the +128 pad
        eNxt = adj[ao + q];
    }
}

__global__ void __launch_bounds__(256, 8)
prop_kernel(const __half* __restrict__ hin, __half* __restrict__ hout,
            const int* __restrict__ row_ptr, const int* __restrict__ adj,
            const float* __restrict__ scale, int N, int E) {
    int wid  = (blockIdx.x * blockDim.x + threadIdx.x) >> 6;
    int lane = threadIdx.x & 63;
    int g    = lane >> 3;
    int q    = lane & 7;
    int nb   = wid << 3;
    if (nb >= N) return;
    int  node  = nb + g;
    bool valid = node < N;
    int  nodeC = valid ? node : (N - 1);
    int cnt = valid ? (row_ptr[nodeC + 1] - row_ptr[nodeC]) : 0;

    float acc[8] = {0.f, 0.f, 0.f, 0.f, 0.f, 0.f, 0.f, 0.f};
    prop_body(hin, row_ptr, adj, nodeC, cnt, g << 3, q, E, acc);

    if (valid) {
        float sc = scale[nodeC];
        float4 o;
        __half2* op = (__half2*)&o;
        op[0] = __float22half2_rn(make_float2(sc * acc[0], sc * acc[1]));
        op[1] = __float22half2_rn(make_float2(sc * acc[2], sc * acc[3]));
        op[2] = __float22half2_rn(make_float2(sc * acc[4], sc * acc[5]));
        op[3] = __float22half2_rn(make_float2(sc * acc[6], sc * acc[7]));
        ((float4*)hout)[(size_t)node * 8 + q] = o;   // coalesced 1KB wave store
    }
}

// ---------------- fused hop 4 + final: out = 2x + (dinv*acc) @ W^T + b - x_pre ----
// Block = 4 waves = 32 nodes. Prop result stays in fp32 regs, staged to an LDS
// tile [32][68]; one barrier; then final_kernel's GEMM mapping (16 lanes x
// float4 per node row -> full-line stores, no write amplification).
__global__ void __launch_bounds__(256, 6)
prop_final_kernel(const __half* __restrict__ hin, const float* __restrict__ x,
                  const float* __restrict__ xp, const float* __restrict__ W,
                  const float* __restrict__ b, float* __restrict__ out,
                  const int* __restrict__ row_ptr, const int* __restrict__ adj,
                  const float* __restrict__ dinv, int N, int E) {
    __shared__ __align__(16) float Wt[64 * 68];   // Wt[k][c] = W[c][k]
    __shared__ __align__(16) float ht[32 * 68];   // h rows for this block
    int t = threadIdx.x;
    int nodeBase = blockIdx.x * 32;

    // stage W^T (identical to final_kernel's loader)
    for (int i = t; i < 1024; i += 256) {
        int c  = i >> 4;
        int k4 = i & 15;
        float4 w4 = ((const float4*)W)[i];
        Wt[(k4 * 4 + 0) * 68 + c] = w4.x;
        Wt[(k4 * 4 + 1) * 68 + c] = w4.y;
        Wt[(k4 * 4 + 2) * 68 + c] = w4.z;
        Wt[(k4 * 4 + 3) * 68 + c] = w4.w;
    }

    // ---- hop 4 (prop body) ----
    int wv   = t >> 6;
    int lane = t & 63;
    int g    = lane >> 3;
    int q    = lane & 7;
    int nl   = wv * 8 + g;                  // node_local 0..31
    int node = nodeBase + nl;
    bool valid = node < N;
    int  nodeC = valid ? node : (N - 1);
    int cnt = valid ? (row_ptr[nodeC + 1] - row_ptr[nodeC]) : 0;

    float acc[8] = {0.f, 0.f, 0.f, 0.f, 0.f, 0.f, 0.f, 0.f};
    prop_body(hin, row_ptr, adj, nodeC, cnt, g << 3, q, E, acc);

    float sc = valid ? dinv[nodeC] : 0.f;   // invalid rows -> zeros in ht
    {
        float* hrow = &ht[nl * 68 + q * 8];
        float4 h0, h1;
        h0.x = sc * acc[0]; h0.y = sc * acc[1]; h0.z = sc * acc[2]; h0.w = sc * acc[3];
        h1.x = sc * acc[4]; h1.y = sc * acc[5]; h1.z = sc * acc[6]; h1.w = sc * acc[7];
        *(float4*)&hrow[0] = h0;
        *(float4*)&hrow[4] = h1;
    }
    __syncthreads();   // Wt staged + all waves' ht rows written

    // ---- final GEMM: 2 passes of 16 nodes x 16 lane-columns ----
    int r0 = t >> 4;                        // 0..15
    int c0 = (t & 15) * 4;
    float4 bv = *(const float4*)&b[c0];
    #pragma unroll
    for (int p = 0; p < 2; ++p) {
        int n = r0 + p * 16;
        int nd = nodeBase + n;
        float4 av = make_float4(0.f, 0.f, 0.f, 0.f);
        #pragma unroll 4
        for (int k4 = 0; k4 < 16; ++k4) {
            float4 h4 = *(const float4*)&ht[n * 68 + k4 * 4];
            float4 w0 = *(const float4*)&Wt[(k4 * 4 + 0) * 68 + c0];
            float4 w1 = *(const float4*)&Wt[(k4 * 4 + 1) * 68 + c0];
            float4 w2 = *(const float4*)&Wt[(k4 * 4 + 2) * 68 + c0];
            float4 w3 = *(const float4*)&Wt[(k4 * 4 + 3) * 68 + c0];
            av.x = fmaf(h4.x, w0.x, av.x); av.y = fmaf(h4.x, w0.y, av.y);
            av.z = fmaf(h4.x, w0.z, av.z); av.w = fmaf(h4.x, w0.w, av.w);
            av.x = fmaf(h4.y, w1.x, av.x); av.y = fmaf(h4.y, w1.y, av.y);
            av.z = fmaf(h4.y, w1.z, av.z); av.w = fmaf(h4.y, w1.w, av.w);
            av.x = fmaf(h4.z, w2.x, av.x); av.y = fmaf(h4.z, w2.y, av.y);
            av.z = fmaf(h4.z, w2.z, av.z); av.w = fmaf(h4.z, w2.w, av.w);
            av.x = fmaf(h4.w, w3.x, av.x); av.y = fmaf(h4.w, w3.y, av.y);
            av.z = fmaf(h4.w, w3.z, av.z); av.w = fmaf(h4.w, w3.w, av.w);
        }
        if (nd < N) {
            int base = nd * 64 + c0;
            float4 xv = *(const float4*)&x[base];
            float4 pv = *(const float4*)&xp[base];
            float4 o;
            o.x = fmaf(2.f, xv.x, av.x + bv.x) - pv.x;
            o.y = fmaf(2.f, xv.y, av.y + bv.y) - pv.y;
            o.z = fmaf(2.f, xv.z, av.z + bv.z) - pv.z;
            o.w = fmaf(2.f, xv.w, av.w + bv.w) - pv.w;
            *(float4*)&out[base] = o;
        }
    }
}

extern "C" void kernel_launch(void* const* d_in, const int* in_sizes, int n_in,
                              void* d_out, int out_size, void* d_ws, size_t ws_size,
                              hipStream_t stream) {
    const float* x    = (const float*)d_in[0];
    const float* xpre = (const float*)d_in[1];
    const int*   ei   = (const int*)d_in[2];
    const float* W    = (const float*)d_in[3];
    const float* b    = (const float*)d_in[4];
    float* out = (float*)d_out;

    const int N = in_sizes[0] / CCH;
    const int E = in_sizes[2] / 2;
    const int* src = ei;
    const int* dst = ei + E;

    const int B     = (N + BKT - 1) / BKT;       // buckets
    const int M     = B * NBLK;                  // count-matrix size
    const int chunk = (E + NBLK - 1) / NBLK;
    const int NB2   = (M + 1023) / 1024;         // scan1 blocks (<=256)

    // workspace partition (256B aligned)
    char* p = (char*)d_ws;
    auto alloc = [&](size_t bytes) -> char* {
        char* r = p;
        p += (bytes + 255) & ~(size_t)255;
        return r;
    };
    int*      cntmat  = (int*)alloc((size_t)M * 4);
    int*      part    = (int*)alloc((size_t)M * 4);
    int*      bsum    = (int*)alloc((size_t)NB2 * 4);
    unsigned* brec    = (unsigned*)alloc((size_t)E * 4);
    int*      adj     = (int*)alloc(((size_t)E + 128) * 4);  // +128 pad for batch prefetch
    int*      row_ptr = (int*)alloc(((size_t)N + 1) * 4);
    float*    dinv    = (float*)alloc((size_t)N * 4);
    float*    dinv2   = (float*)alloc((size_t)N * 4);
    __half*   xh      = (__half*)alloc((size_t)N * CCH * 2);
    __half*   g0      = (__half*)alloc((size_t)N * CCH * 2);
    __half*   g1      = (__half*)alloc((size_t)N * CCH * 2);

    countA<<<NBLK, 256, 0, stream>>>(dst, cntmat, E, chunk, B);
    scan1 <<<NB2, 256, 0, stream>>>(cntmat, part, bsum, M);
    partA <<<NBLK, 256, 0, stream>>>(src, dst, part, bsum, brec, E, chunk, B, NB2);
    buildB<<<B, 256, 0, stream>>>(brec, part, bsum, row_ptr, adj, dinv, dinv2,
                                  x, xh, N, B, E, NB2);

    const int nwave = (N + 7) / 8;               // 8 nodes per wave
    const int pgrid = (nwave + 3) / 4;           // 4 waves per 256-thread block
    prop_kernel<<<pgrid, 256, 0, stream>>>(xh, g0, row_ptr, adj, dinv2, N, E); // hop 1
    prop_kernel<<<pgrid, 256, 0, stream>>>(g0, g1, row_ptr, adj, dinv2, N, E); // hop 2
    prop_kernel<<<pgrid, 256, 0, stream>>>(g1, g0, row_ptr, adj, dinv2, N, E); // hop 3
    // hop 4 + final fused (reads g0, writes out directly; g1 unused this round)
    prop_final_kernel<<<(N + 31) / 32, 256, 0, stream>>>(g0, x, xpre, W, b, out,
                                                         row_ptr, adj, dinv, N, E);
    (void)g1;
}